// Round 2
// baseline (624.536 us; speedup 1.0000x reference)
//
#include <hip/hip_runtime.h>
#include <hip/hip_fp16.h>
#include <math.h>

typedef _Float16 half4_t __attribute__((ext_vector_type(4)));
typedef _Float16 half8_t __attribute__((ext_vector_type(8)));
typedef float float4_t __attribute__((ext_vector_type(4)));

static constexpr int DMODEL = 1024;
static constexpr int SLEN   = 2048;
static constexpr int NHEADS = 16;
static constexpr int MTOT   = 4096;   // B * S

// ---------------- f32 -> f16 convert ----------------
__global__ __launch_bounds__(256) void cvt_kernel(const float* __restrict__ src,
                                                  _Float16* __restrict__ dst, int n4) {
  int i = blockIdx.x * 256 + threadIdx.x;
  if (i < n4) {
    float4_t v = ((const float4_t*)src)[i];
    half4_t h;
    h[0] = (_Float16)v[0]; h[1] = (_Float16)v[1];
    h[2] = (_Float16)v[2]; h[3] = (_Float16)v[3];
    ((half4_t*)dst)[i] = h;
  }
}

// ---------------- NT GEMM core: C[64x64 per wave] = A[M,K] * W[N,K]^T -------
// A and B fragments use the SAME per-lane k-map, so the result is invariant
// to the exact MFMA k-permutation. D layout (HW-verified): col=lane&15,
// row=4*(lane>>4)+reg.
__device__ __forceinline__ void gemm_acc_64x64(
    const _Float16* __restrict__ A, const _Float16* __restrict__ W, int K,
    int row0, int col0, int lr, int lg, float4_t acc[4][4]) {
  const _Float16* Ap = A + (size_t)(row0 + lr) * K + 8 * lg;
  const _Float16* Wp = W + (size_t)(col0 + lr) * K + 8 * lg;
  for (int k0 = 0; k0 < K; k0 += 32) {
    half8_t af[4], bf[4];
#pragma unroll
    for (int i = 0; i < 4; i++)
      af[i] = *(const half8_t*)(Ap + (size_t)(16 * i) * K + k0);
#pragma unroll
    for (int j = 0; j < 4; j++)
      bf[j] = *(const half8_t*)(Wp + (size_t)(16 * j) * K + k0);
#pragma unroll
    for (int i = 0; i < 4; i++)
#pragma unroll
      for (int j = 0; j < 4; j++)
        acc[i][j] = __builtin_amdgcn_mfma_f32_16x16x32_f16(af[i], bf[j], acc[i][j], 0, 0, 0);
  }
}

// ---------------- fused QKV + MLP1 projections ----------------
__global__ __launch_bounds__(256) void proj_kernel(
    const _Float16* __restrict__ xh,
    const _Float16* __restrict__ wqh, const _Float16* __restrict__ wkh,
    const _Float16* __restrict__ wvh, const _Float16* __restrict__ wm1h,
    const float* __restrict__ bq, const float* __restrict__ bk,
    const float* __restrict__ bv, const float* __restrict__ bm1,
    _Float16* __restrict__ Qh, _Float16* __restrict__ Kh,
    _Float16* __restrict__ Vh, _Float16* __restrict__ Hm) {
  int z = blockIdx.z;
  const _Float16* W; const float* bias; _Float16* out; int N; bool act = false;
  if (z == 0)      { W = wqh;  bias = bq;  out = Qh; N = 1024; }
  else if (z == 1) { W = wkh;  bias = bk;  out = Kh; N = 1024; }
  else if (z == 2) { W = wvh;  bias = bv;  out = Vh; N = 1024; }
  else             { W = wm1h; bias = bm1; out = Hm; N = 512; act = true; }
  int colB = blockIdx.y * 128;
  if (colB >= N) return;
  int wave = threadIdx.x >> 6, lane = threadIdx.x & 63;
  int lr = lane & 15, lg = lane >> 4;
  int row0 = blockIdx.x * 128 + (wave >> 1) * 64;
  int col0 = colB + (wave & 1) * 64;
  float4_t acc[4][4];
#pragma unroll
  for (int i = 0; i < 4; i++)
#pragma unroll
    for (int j = 0; j < 4; j++) acc[i][j] = (float4_t){0.f, 0.f, 0.f, 0.f};
  gemm_acc_64x64(xh, W, 1024, row0, col0, lr, lg, acc);
#pragma unroll
  for (int j = 0; j < 4; j++) {
    int col = col0 + 16 * j + lr;
    float bb = bias[col];
#pragma unroll
    for (int i = 0; i < 4; i++) {
#pragma unroll
      for (int r = 0; r < 4; r++) {
        int row = row0 + 16 * i + 4 * lg + r;
        float v = acc[i][j][r] + bb;
        if (act) v = 0.5f * v * (1.0f + erff(v * 0.70710678118f));
        out[(size_t)row * N + col] = (_Float16)v;
      }
    }
  }
}

// ---------------- output projection (writes f32 to d_out) ----------------
__global__ __launch_bounds__(256) void outproj_kernel(
    const _Float16* __restrict__ ctxh, const _Float16* __restrict__ woh,
    const float* __restrict__ bo, float* __restrict__ out) {
  int wave = threadIdx.x >> 6, lane = threadIdx.x & 63;
  int lr = lane & 15, lg = lane >> 4;
  int row0 = blockIdx.x * 128 + (wave >> 1) * 64;
  int col0 = blockIdx.y * 128 + (wave & 1) * 64;
  float4_t acc[4][4];
#pragma unroll
  for (int i = 0; i < 4; i++)
#pragma unroll
    for (int j = 0; j < 4; j++) acc[i][j] = (float4_t){0.f, 0.f, 0.f, 0.f};
  gemm_acc_64x64(ctxh, woh, 1024, row0, col0, lr, lg, acc);
#pragma unroll
  for (int j = 0; j < 4; j++) {
    int col = col0 + 16 * j + lr;
    float bb = bo[col];
#pragma unroll
    for (int i = 0; i < 4; i++) {
#pragma unroll
      for (int r = 0; r < 4; r++) {
        int row = row0 + 16 * i + 4 * lg + r;
        out[(size_t)row * 1024 + col] = acc[i][j][r] + bb;
      }
    }
  }
}

// ---------------- mechanism logits: Hm[4096,512] . Wm2[512] + bm2 ----------
__global__ __launch_bounds__(256) void mech_logits_kernel(
    const _Float16* __restrict__ Hm, const float* __restrict__ Wm2,
    const float* __restrict__ bm2, float* __restrict__ logits) {
  int wave = threadIdx.x >> 6, lane = threadIdx.x & 63;
  int row = blockIdx.x * 4 + wave;
  half8_t hv = *(const half8_t*)(Hm + (size_t)row * 512 + lane * 8);
  float4_t w0 = *(const float4_t*)(Wm2 + lane * 8);
  float4_t w1 = *(const float4_t*)(Wm2 + lane * 8 + 4);
  float s = 0.f;
#pragma unroll
  for (int j = 0; j < 4; j++) s += (float)hv[j] * w0[j];
#pragma unroll
  for (int j = 0; j < 4; j++) s += (float)hv[4 + j] * w1[j];
#pragma unroll
  for (int m = 32; m >= 1; m >>= 1) s += __shfl_xor(s, m, 64);
  if (lane == 0) logits[row] = s + bm2[0];
}

// ---------------- per-batch softmax over 2048 logits ----------------
__global__ __launch_bounds__(256) void mech_softmax_kernel(
    const float* __restrict__ logits, float* __restrict__ mech_ws,
    float* __restrict__ mech_out) {
  int b = blockIdx.x;
  int t = threadIdx.x;
  int wave = t >> 6, lane = t & 63;
  __shared__ float redmax[4];
  __shared__ float redsum[4];
  const float4_t* L4 = (const float4_t*)(logits + (size_t)b * 2048);
  float4_t v0 = L4[2 * t], v1 = L4[2 * t + 1];
  float mx = fmaxf(fmaxf(fmaxf(v0[0], v0[1]), fmaxf(v0[2], v0[3])),
                   fmaxf(fmaxf(v1[0], v1[1]), fmaxf(v1[2], v1[3])));
#pragma unroll
  for (int m = 32; m >= 1; m >>= 1) mx = fmaxf(mx, __shfl_xor(mx, m, 64));
  if (lane == 0) redmax[wave] = mx;
  __syncthreads();
  mx = fmaxf(fmaxf(redmax[0], redmax[1]), fmaxf(redmax[2], redmax[3]));
  float e[8];
  float s = 0.f;
#pragma unroll
  for (int j = 0; j < 4; j++) { e[j] = __expf(v0[j] - mx); s += e[j]; }
#pragma unroll
  for (int j = 0; j < 4; j++) { e[4 + j] = __expf(v1[j] - mx); s += e[4 + j]; }
#pragma unroll
  for (int m = 32; m >= 1; m >>= 1) s += __shfl_xor(s, m, 64);
  if (lane == 0) redsum[wave] = s;
  __syncthreads();
  s = redsum[0] + redsum[1] + redsum[2] + redsum[3];
  float inv = 1.0f / s;
  size_t base = (size_t)b * 2048 + (size_t)t * 8;
#pragma unroll
  for (int j = 0; j < 8; j++) {
    float val = e[j] * inv;
    mech_ws[base + j] = val;
    mech_out[base + j] = val;
  }
}

// ---------------- V transpose: Vh[4096,1024] -> VT[B*H][64][2048] ----------
__global__ __launch_bounds__(256) void vtrans_kernel(const _Float16* __restrict__ Vh,
                                                     _Float16* __restrict__ VT) {
  int bh = blockIdx.y;
  int b = bh >> 4, h = bh & 15;
  int k0 = blockIdx.x * 64;
  __shared__ _Float16 tile[64][65];
  int t = threadIdx.x;
#pragma unroll
  for (int rep = 0; rep < 16; rep++) {
    int idx = rep * 256 + t;
    int k = idx >> 6, d = idx & 63;
    tile[d][k] = Vh[(size_t)(b * 2048 + k0 + k) * 1024 + h * 64 + d];
  }
  __syncthreads();
#pragma unroll
  for (int rep = 0; rep < 16; rep++) {
    int idx = rep * 256 + t;
    int d = idx >> 6, k = idx & 63;
    VT[((size_t)bh * 64 + d) * 2048 + k0 + k] = tile[d][k];
  }
}

// ---------------- flash attention with mechanism bias ----------------
// swapped QK^T: s = mfma(K-frag, Q-frag) -> lane holds P[q=lane&15][k=4*lg+r],
// which IS the A-fragment of mfma_f32_16x16x16f16 for the PV step.
__global__ __launch_bounds__(256) void attn_kernel(
    const _Float16* __restrict__ Qh, const _Float16* __restrict__ Kh,
    const _Float16* __restrict__ VT, const float* __restrict__ mech,
    const int* __restrict__ mask, _Float16* __restrict__ ctxh) {
  __shared__ float bias_s[2048];
  int bh = blockIdx.y;
  int b = bh >> 4, h = bh & 15;
  for (int i = threadIdx.x; i < 2048; i += 256)
    bias_s[i] = 2.0f * mech[(size_t)b * 2048 + i] + (mask[(size_t)b * 2048 + i] != 0 ? 0.0f : -1e30f);
  __syncthreads();
  int wave = threadIdx.x >> 6, lane = threadIdx.x & 63;
  int lr = lane & 15, lg = lane >> 4;
  int q0 = blockIdx.x * 64 + wave * 16;

  const _Float16* Qp = Qh + (size_t)(b * 2048 + q0 + lr) * 1024 + h * 64 + 8 * lg;
  half8_t qf0 = *(const half8_t*)Qp;
  half8_t qf1 = *(const half8_t*)(Qp + 32);
  const _Float16* Kp = Kh + (size_t)(b * 2048 + lr) * 1024 + h * 64 + 8 * lg;
  const _Float16* Vp = VT + ((size_t)bh * 64 + lr) * 2048 + 4 * lg;

  float m_run = -1e30f, l_run = 0.0f;
  float4_t cacc[4];
#pragma unroll
  for (int dd = 0; dd < 4; dd++) cacc[dd] = (float4_t){0.f, 0.f, 0.f, 0.f};

  for (int k0 = 0; k0 < 2048; k0 += 16) {
    half8_t kf0 = *(const half8_t*)(Kp + (size_t)k0 * 1024);
    half8_t kf1 = *(const half8_t*)(Kp + (size_t)k0 * 1024 + 32);
    float4_t s = (float4_t){0.f, 0.f, 0.f, 0.f};
    s = __builtin_amdgcn_mfma_f32_16x16x32_f16(kf0, qf0, s, 0, 0, 0);
    s = __builtin_amdgcn_mfma_f32_16x16x32_f16(kf1, qf1, s, 0, 0, 0);
    float sc0 = s[0] * 0.125f + bias_s[k0 + 4 * lg + 0];
    float sc1 = s[1] * 0.125f + bias_s[k0 + 4 * lg + 1];
    float sc2 = s[2] * 0.125f + bias_s[k0 + 4 * lg + 2];
    float sc3 = s[3] * 0.125f + bias_s[k0 + 4 * lg + 3];
    float tm = fmaxf(fmaxf(sc0, sc1), fmaxf(sc2, sc3));
    tm = fmaxf(tm, __shfl_xor(tm, 16, 64));
    tm = fmaxf(tm, __shfl_xor(tm, 32, 64));
    float m_new = fmaxf(m_run, tm);
    float p0 = __expf(sc0 - m_new);
    float p1 = __expf(sc1 - m_new);
    float p2 = __expf(sc2 - m_new);
    float p3 = __expf(sc3 - m_new);
    float ts = p0 + p1 + p2 + p3;
    ts += __shfl_xor(ts, 16, 64);
    ts += __shfl_xor(ts, 32, 64);
    float alpha = __expf(m_run - m_new);
    l_run = l_run * alpha + ts;
    m_run = m_new;
    half4_t pa;
    pa[0] = (_Float16)p0; pa[1] = (_Float16)p1;
    pa[2] = (_Float16)p2; pa[3] = (_Float16)p3;
    int rbase = 4 * lg;
    float a0 = __shfl(alpha, rbase + 0, 64);
    float a1 = __shfl(alpha, rbase + 1, 64);
    float a2 = __shfl(alpha, rbase + 2, 64);
    float a3 = __shfl(alpha, rbase + 3, 64);
#pragma unroll
    for (int dd = 0; dd < 4; dd++) {
      half4_t vf = *(const half4_t*)(Vp + (size_t)(16 * dd) * 2048 + k0);
      float4_t c = cacc[dd];
      c[0] *= a0; c[1] *= a1; c[2] *= a2; c[3] *= a3;
      cacc[dd] = __builtin_amdgcn_mfma_f32_16x16x16f16(pa, vf, c, 0, 0, 0);
    }
  }
  float linv = 1.0f / l_run;
  int rbase = 4 * lg;
  float i0 = __shfl(linv, rbase + 0, 64);
  float i1 = __shfl(linv, rbase + 1, 64);
  float i2 = __shfl(linv, rbase + 2, 64);
  float i3 = __shfl(linv, rbase + 3, 64);
  float invs[4] = {i0, i1, i2, i3};
#pragma unroll
  for (int dd = 0; dd < 4; dd++) {
#pragma unroll
    for (int r = 0; r < 4; r++) {
      size_t idx = (size_t)(b * 2048 + q0 + rbase + r) * 1024 + h * 64 + 16 * dd + lr;
      ctxh[idx] = (_Float16)(cacc[dd][r] * invs[r]);
    }
  }
}

extern "C" void kernel_launch(void* const* d_in, const int* in_sizes, int n_in,
                              void* d_out, int out_size, void* d_ws, size_t ws_size,
                              hipStream_t stream) {
  const float* x    = (const float*)d_in[0];
  const int*   mask = (const int*)d_in[1];
  const float* Wq   = (const float*)d_in[2];
  const float* bq   = (const float*)d_in[3];
  const float* Wk   = (const float*)d_in[4];
  const float* bk   = (const float*)d_in[5];
  const float* Wv   = (const float*)d_in[6];
  const float* bv   = (const float*)d_in[7];
  const float* Wo   = (const float*)d_in[8];
  const float* bo   = (const float*)d_in[9];
  const float* Wm1  = (const float*)d_in[10];
  const float* bm1  = (const float*)d_in[11];
  const float* Wm2  = (const float*)d_in[12];
  const float* bm2  = (const float*)d_in[13];
  float* outp = (float*)d_out;
  float* mech_out = outp + (size_t)MTOT * DMODEL;

  char* ws = (char*)d_ws;
  _Float16* xh   = (_Float16*)(ws + 0);
  _Float16* wqh  = (_Float16*)(ws + 8388608);
  _Float16* wkh  = (_Float16*)(ws + 10485760);
  _Float16* wvh  = (_Float16*)(ws + 12582912);
  _Float16* woh  = (_Float16*)(ws + 14680064);
  _Float16* wm1h = (_Float16*)(ws + 16777216);
  _Float16* Qh   = (_Float16*)(ws + 17825792);
  _Float16* Kh   = (_Float16*)(ws + 26214400);
  _Float16* Vh   = (_Float16*)(ws + 34603008);
  _Float16* VT   = (_Float16*)(ws + 42991616);
  _Float16* ctxh = (_Float16*)(ws + 51380224);
  _Float16* Hm   = (_Float16*)(ws + 59768832);
  float* logits  = (float*)(ws + 63963136);
  float* mech_ws = (float*)(ws + 63979520);

  hipLaunchKernelGGL(cvt_kernel, dim3(4096), dim3(256), 0, stream, x, xh, 1048576);
  hipLaunchKernelGGL(cvt_kernel, dim3(1024), dim3(256), 0, stream, Wq, wqh, 262144);
  hipLaunchKernelGGL(cvt_kernel, dim3(1024), dim3(256), 0, stream, Wk, wkh, 262144);
  hipLaunchKernelGGL(cvt_kernel, dim3(1024), dim3(256), 0, stream, Wv, wvh, 262144);
  hipLaunchKernelGGL(cvt_kernel, dim3(1024), dim3(256), 0, stream, Wo, woh, 262144);
  hipLaunchKernelGGL(cvt_kernel, dim3(512), dim3(256), 0, stream, Wm1, wm1h, 131072);

  hipLaunchKernelGGL(proj_kernel, dim3(32, 8, 4), dim3(256), 0, stream,
                     xh, wqh, wkh, wvh, wm1h, bq, bk, bv, bm1, Qh, Kh, Vh, Hm);

  hipLaunchKernelGGL(mech_logits_kernel, dim3(1024), dim3(256), 0, stream,
                     Hm, Wm2, bm2, logits);
  hipLaunchKernelGGL(mech_softmax_kernel, dim3(2), dim3(256), 0, stream,
                     logits, mech_ws, mech_out);

  hipLaunchKernelGGL(vtrans_kernel, dim3(32, 32), dim3(256), 0, stream, Vh, VT);

  hipLaunchKernelGGL(attn_kernel, dim3(32, 32), dim3(256), 0, stream,
                     Qh, Kh, VT, mech_ws, mask, ctxh);

  hipLaunchKernelGGL(outproj_kernel, dim3(32, 8), dim3(256), 0, stream,
                     ctxh, woh, bo, outp);
}

// Round 3
// 611.980 us; speedup vs baseline: 1.0205x; 1.0205x over previous
//
#include <hip/hip_runtime.h>
#include <hip/hip_fp16.h>
#include <math.h>

typedef _Float16 half4_t __attribute__((ext_vector_type(4)));
typedef _Float16 half8_t __attribute__((ext_vector_type(8)));
typedef float float4_t __attribute__((ext_vector_type(4)));

static constexpr int DMODEL = 1024;
static constexpr int SLEN   = 2048;
static constexpr int NHEADS = 16;
static constexpr int MTOT   = 4096;   // B * S

// ---------------- fused f32 -> f16 convert (x + all 5 weights) ----------------
// y=0: x (4096 blocks of 256 float4). y=1: weights chained:
//   wq [0,1024) wk [1024,2048) wv [2048,3072) wo [3072,4096) wm1 [4096,4608)
__global__ __launch_bounds__(256) void cvt_all_kernel(
    const float* __restrict__ x,
    const float* __restrict__ Wq, const float* __restrict__ Wk,
    const float* __restrict__ Wv, const float* __restrict__ Wo,
    const float* __restrict__ Wm1,
    _Float16* __restrict__ xh, _Float16* __restrict__ wqh,
    _Float16* __restrict__ wkh, _Float16* __restrict__ wvh,
    _Float16* __restrict__ woh, _Float16* __restrict__ wm1h) {
  int bx = blockIdx.x;
  const float* src; _Float16* dst; int lb;
  if (blockIdx.y == 0) {
    if (bx >= 4096) return;
    src = x; dst = xh; lb = bx;
  } else {
    if (bx < 1024)      { src = Wq;  dst = wqh;  lb = bx; }
    else if (bx < 2048) { src = Wk;  dst = wkh;  lb = bx - 1024; }
    else if (bx < 3072) { src = Wv;  dst = wvh;  lb = bx - 2048; }
    else if (bx < 4096) { src = Wo;  dst = woh;  lb = bx - 3072; }
    else                { src = Wm1; dst = wm1h; lb = bx - 4096; }
  }
  int i = lb * 256 + threadIdx.x;
  float4_t v = ((const float4_t*)src)[i];
  half4_t h;
  h[0] = (_Float16)v[0]; h[1] = (_Float16)v[1];
  h[2] = (_Float16)v[2]; h[3] = (_Float16)v[3];
  ((half4_t*)dst)[i] = h;
}

// ---------------- NT GEMM core: C[64x64 per wave] = A[M,K] * W[N,K]^T -------
// A and B fragments use the SAME per-lane k-map -> k-permutation invariant.
// D layout (HW-verified): col=lane&15, row=4*(lane>>4)+reg.
__device__ __forceinline__ void gemm_acc_64x64(
    const _Float16* __restrict__ A, const _Float16* __restrict__ W, int K,
    int row0, int col0, int lr, int lg, float4_t acc[4][4]) {
  const _Float16* Ap = A + (size_t)(row0 + lr) * K + 8 * lg;
  const _Float16* Wp = W + (size_t)(col0 + lr) * K + 8 * lg;
  for (int k0 = 0; k0 < K; k0 += 32) {
    half8_t af[4], bf[4];
#pragma unroll
    for (int i = 0; i < 4; i++)
      af[i] = *(const half8_t*)(Ap + (size_t)(16 * i) * K + k0);
#pragma unroll
    for (int j = 0; j < 4; j++)
      bf[j] = *(const half8_t*)(Wp + (size_t)(16 * j) * K + k0);
#pragma unroll
    for (int i = 0; i < 4; i++)
#pragma unroll
      for (int j = 0; j < 4; j++)
        acc[i][j] = __builtin_amdgcn_mfma_f32_16x16x32_f16(af[i], bf[j], acc[i][j], 0, 0, 0);
  }
}

// ---------------- fused QKV + MLP1 projections ----------------
__global__ __launch_bounds__(256) void proj_kernel(
    const _Float16* __restrict__ xh,
    const _Float16* __restrict__ wqh, const _Float16* __restrict__ wkh,
    const _Float16* __restrict__ wvh, const _Float16* __restrict__ wm1h,
    const float* __restrict__ bq, const float* __restrict__ bk,
    const float* __restrict__ bv, const float* __restrict__ bm1,
    _Float16* __restrict__ Qh, _Float16* __restrict__ Kh,
    _Float16* __restrict__ Vh, _Float16* __restrict__ Hm) {
  int z = blockIdx.z;
  const _Float16* W; const float* bias; _Float16* out; int N; bool act = false;
  if (z == 0)      { W = wqh;  bias = bq;  out = Qh; N = 1024; }
  else if (z == 1) { W = wkh;  bias = bk;  out = Kh; N = 1024; }
  else if (z == 2) { W = wvh;  bias = bv;  out = Vh; N = 1024; }
  else             { W = wm1h; bias = bm1; out = Hm; N = 512; act = true; }
  int colB = blockIdx.y * 128;
  if (colB >= N) return;
  int wave = threadIdx.x >> 6, lane = threadIdx.x & 63;
  int lr = lane & 15, lg = lane >> 4;
  int row0 = blockIdx.x * 128 + (wave >> 1) * 64;
  int col0 = colB + (wave & 1) * 64;
  float4_t acc[4][4];
#pragma unroll
  for (int i = 0; i < 4; i++)
#pragma unroll
    for (int j = 0; j < 4; j++) acc[i][j] = (float4_t){0.f, 0.f, 0.f, 0.f};
  gemm_acc_64x64(xh, W, 1024, row0, col0, lr, lg, acc);
#pragma unroll
  for (int j = 0; j < 4; j++) {
    int col = col0 + 16 * j + lr;
    float bb = bias[col];
#pragma unroll
    for (int i = 0; i < 4; i++) {
#pragma unroll
      for (int r = 0; r < 4; r++) {
        int row = row0 + 16 * i + 4 * lg + r;
        float v = acc[i][j][r] + bb;
        if (act) v = 0.5f * v * (1.0f + erff(v * 0.70710678118f));
        out[(size_t)row * N + col] = (_Float16)v;
      }
    }
  }
}

// ---------------- output projection (writes f32 to d_out) ----------------
__global__ __launch_bounds__(256) void outproj_kernel(
    const _Float16* __restrict__ ctxh, const _Float16* __restrict__ woh,
    const float* __restrict__ bo, float* __restrict__ out) {
  int wave = threadIdx.x >> 6, lane = threadIdx.x & 63;
  int lr = lane & 15, lg = lane >> 4;
  int row0 = blockIdx.x * 128 + (wave >> 1) * 64;
  int col0 = blockIdx.y * 128 + (wave & 1) * 64;
  float4_t acc[4][4];
#pragma unroll
  for (int i = 0; i < 4; i++)
#pragma unroll
    for (int j = 0; j < 4; j++) acc[i][j] = (float4_t){0.f, 0.f, 0.f, 0.f};
  gemm_acc_64x64(ctxh, woh, 1024, row0, col0, lr, lg, acc);
#pragma unroll
  for (int j = 0; j < 4; j++) {
    int col = col0 + 16 * j + lr;
    float bb = bo[col];
#pragma unroll
    for (int i = 0; i < 4; i++) {
#pragma unroll
      for (int r = 0; r < 4; r++) {
        int row = row0 + 16 * i + 4 * lg + r;
        out[(size_t)row * 1024 + col] = acc[i][j][r] + bb;
      }
    }
  }
}

// ---------------- mechanism logits: Hm[4096,512] . Wm2[512] + bm2 ----------
__global__ __launch_bounds__(256) void mech_logits_kernel(
    const _Float16* __restrict__ Hm, const float* __restrict__ Wm2,
    const float* __restrict__ bm2, float* __restrict__ logits) {
  int wave = threadIdx.x >> 6, lane = threadIdx.x & 63;
  int row = blockIdx.x * 4 + wave;
  half8_t hv = *(const half8_t*)(Hm + (size_t)row * 512 + lane * 8);
  float4_t w0 = *(const float4_t*)(Wm2 + lane * 8);
  float4_t w1 = *(const float4_t*)(Wm2 + lane * 8 + 4);
  float s = 0.f;
#pragma unroll
  for (int j = 0; j < 4; j++) s += (float)hv[j] * w0[j];
#pragma unroll
  for (int j = 0; j < 4; j++) s += (float)hv[4 + j] * w1[j];
#pragma unroll
  for (int m = 32; m >= 1; m >>= 1) s += __shfl_xor(s, m, 64);
  if (lane == 0) logits[row] = s + bm2[0];
}

// ---------------- per-batch softmax over 2048 logits ----------------
__global__ __launch_bounds__(256) void mech_softmax_kernel(
    const float* __restrict__ logits, float* __restrict__ mech_ws,
    float* __restrict__ mech_out) {
  int b = blockIdx.x;
  int t = threadIdx.x;
  int wave = t >> 6, lane = t & 63;
  __shared__ float redmax[4];
  __shared__ float redsum[4];
  const float4_t* L4 = (const float4_t*)(logits + (size_t)b * 2048);
  float4_t v0 = L4[2 * t], v1 = L4[2 * t + 1];
  float mx = fmaxf(fmaxf(fmaxf(v0[0], v0[1]), fmaxf(v0[2], v0[3])),
                   fmaxf(fmaxf(v1[0], v1[1]), fmaxf(v1[2], v1[3])));
#pragma unroll
  for (int m = 32; m >= 1; m >>= 1) mx = fmaxf(mx, __shfl_xor(mx, m, 64));
  if (lane == 0) redmax[wave] = mx;
  __syncthreads();
  mx = fmaxf(fmaxf(redmax[0], redmax[1]), fmaxf(redmax[2], redmax[3]));
  float e[8];
  float s = 0.f;
#pragma unroll
  for (int j = 0; j < 4; j++) { e[j] = __expf(v0[j] - mx); s += e[j]; }
#pragma unroll
  for (int j = 0; j < 4; j++) { e[4 + j] = __expf(v1[j] - mx); s += e[4 + j]; }
#pragma unroll
  for (int m = 32; m >= 1; m >>= 1) s += __shfl_xor(s, m, 64);
  if (lane == 0) redsum[wave] = s;
  __syncthreads();
  s = redsum[0] + redsum[1] + redsum[2] + redsum[3];
  float inv = 1.0f / s;
  size_t base = (size_t)b * 2048 + (size_t)t * 8;
#pragma unroll
  for (int j = 0; j < 8; j++) {
    float val = e[j] * inv;
    mech_ws[base + j] = val;
    mech_out[base + j] = val;
  }
}

// ---------------- V transpose: Vh[4096,1024] -> VT[B*H][64][2048] ----------
__global__ __launch_bounds__(256) void vtrans_kernel(const _Float16* __restrict__ Vh,
                                                     _Float16* __restrict__ VT) {
  int bh = blockIdx.y;
  int b = bh >> 4, h = bh & 15;
  int k0 = blockIdx.x * 64;
  __shared__ _Float16 tile[64][65];
  int t = threadIdx.x;
#pragma unroll
  for (int rep = 0; rep < 16; rep++) {
    int idx = rep * 256 + t;
    int k = idx >> 6, d = idx & 63;
    tile[d][k] = Vh[(size_t)(b * 2048 + k0 + k) * 1024 + h * 64 + d];
  }
  __syncthreads();
#pragma unroll
  for (int rep = 0; rep < 16; rep++) {
    int idx = rep * 256 + t;
    int d = idx >> 6, k = idx & 63;
    VT[((size_t)bh * 64 + d) * 2048 + k0 + k] = tile[d][k];
  }
}

// ---------------- flash attention with mechanism bias ----------------
// swapped QK^T: s = mfma(K-frag, Q-frag) -> lane holds P[q=lane&15][k=4*lg+r],
// which IS the A-fragment of mfma_f32_16x16x16f16 for the PV step.
// 64-key tiles + defer-max (THR=8) + per-lane partial l: common path has
// only 2 cross-lane shuffles per 64 keys (was ~32).
__global__ __launch_bounds__(256) void attn_kernel(
    const _Float16* __restrict__ Qh, const _Float16* __restrict__ Kh,
    const _Float16* __restrict__ VT, const float* __restrict__ mech,
    const int* __restrict__ mask, _Float16* __restrict__ ctxh) {
  __shared__ float bias_s[2048];
  int bh = blockIdx.y;
  int b = bh >> 4, h = bh & 15;
  for (int i = threadIdx.x; i < 2048; i += 256)
    bias_s[i] = 2.0f * mech[(size_t)b * 2048 + i] + (mask[(size_t)b * 2048 + i] != 0 ? 0.0f : -1e30f);
  __syncthreads();
  int wave = threadIdx.x >> 6, lane = threadIdx.x & 63;
  int lr = lane & 15, lg = lane >> 4;
  int q0 = blockIdx.x * 64 + wave * 16;

  const _Float16* Qp = Qh + (size_t)(b * 2048 + q0 + lr) * 1024 + h * 64 + 8 * lg;
  half8_t qf0 = *(const half8_t*)Qp;
  half8_t qf1 = *(const half8_t*)(Qp + 32);
  const _Float16* Kp = Kh + (size_t)(b * 2048 + lr) * 1024 + h * 64 + 8 * lg;
  const _Float16* Vp = VT + ((size_t)bh * 64 + lr) * 2048 + 4 * lg;

  float m_run = -1e30f;   // per-lane, indexed by q = lr
  float l_run = 0.0f;     // per-lane PARTIAL sum (this lane's keys only)
  float4_t cacc[4];
#pragma unroll
  for (int dd = 0; dd < 4; dd++) cacc[dd] = (float4_t){0.f, 0.f, 0.f, 0.f};

  for (int k0 = 0; k0 < 2048; k0 += 64) {
    // --- K loads for 4 sub-tiles ---
    half8_t kf[4][2];
#pragma unroll
    for (int t = 0; t < 4; t++) {
      const _Float16* kp = Kp + (size_t)(k0 + 16 * t) * 1024;
      kf[t][0] = *(const half8_t*)kp;
      kf[t][1] = *(const half8_t*)(kp + 32);
    }
    float4_t bias4[4];
#pragma unroll
    for (int t = 0; t < 4; t++)
      bias4[t] = *(const float4_t*)&bias_s[k0 + 16 * t + 4 * lg];
    // --- QK^T ---
    float4_t s[4];
#pragma unroll
    for (int t = 0; t < 4; t++) {
      float4_t z = (float4_t){0.f, 0.f, 0.f, 0.f};
      z = __builtin_amdgcn_mfma_f32_16x16x32_f16(kf[t][0], qf0, z, 0, 0, 0);
      z = __builtin_amdgcn_mfma_f32_16x16x32_f16(kf[t][1], qf1, z, 0, 0, 0);
      s[t] = z;
    }
    // --- scores = s/8 + bias ---
#pragma unroll
    for (int t = 0; t < 4; t++)
#pragma unroll
      for (int r = 0; r < 4; r++)
        s[t][r] = s[t][r] * 0.125f + bias4[t][r];
    // --- tile max for this lane's q-row (reduce 16 values + 2 shuffles) ---
    float tm0 = fmaxf(fmaxf(s[0][0], s[0][1]), fmaxf(s[0][2], s[0][3]));
    float tm1 = fmaxf(fmaxf(s[1][0], s[1][1]), fmaxf(s[1][2], s[1][3]));
    float tm2 = fmaxf(fmaxf(s[2][0], s[2][1]), fmaxf(s[2][2], s[2][3]));
    float tm3 = fmaxf(fmaxf(s[3][0], s[3][1]), fmaxf(s[3][2], s[3][3]));
    float tm = fmaxf(fmaxf(tm0, tm1), fmaxf(tm2, tm3));
    tm = fmaxf(tm, __shfl_xor(tm, 16, 64));
    tm = fmaxf(tm, __shfl_xor(tm, 32, 64));
    // --- defer-max: rescale only when max grew by > 8 ---
    if (__any(tm > m_run + 8.0f)) {
      float m_new = fmaxf(m_run, tm);
      float alpha = __expf(m_run - m_new);
      l_run *= alpha;
      m_run = m_new;
      int rbase = 4 * lg;
      float a0 = __shfl(alpha, rbase + 0, 64);
      float a1 = __shfl(alpha, rbase + 1, 64);
      float a2 = __shfl(alpha, rbase + 2, 64);
      float a3 = __shfl(alpha, rbase + 3, 64);
#pragma unroll
      for (int dd = 0; dd < 4; dd++) {
        cacc[dd][0] *= a0; cacc[dd][1] *= a1;
        cacc[dd][2] *= a2; cacc[dd][3] *= a3;
      }
    }
    // --- P = exp(sc - m_run), per-lane l accumulation, f16 pack ---
    half4_t pa[4];
#pragma unroll
    for (int t = 0; t < 4; t++) {
#pragma unroll
      for (int r = 0; r < 4; r++) {
        float p = __expf(s[t][r] - m_run);
        l_run += p;
        pa[t][r] = (_Float16)p;
      }
    }
    // --- PV ---
#pragma unroll
    for (int dd = 0; dd < 4; dd++) {
#pragma unroll
      for (int t = 0; t < 4; t++) {
        half4_t vf = *(const half4_t*)(Vp + (size_t)(16 * dd) * 2048 + k0 + 16 * t);
        cacc[dd] = __builtin_amdgcn_mfma_f32_16x16x16f16(pa[t], vf, cacc[dd], 0, 0, 0);
      }
    }
  }
  // --- finalize: reduce per-lane partial l across lane groups ---
  l_run += __shfl_xor(l_run, 16, 64);
  l_run += __shfl_xor(l_run, 32, 64);
  float linv = 1.0f / l_run;
  int rbase = 4 * lg;
  float i0 = __shfl(linv, rbase + 0, 64);
  float i1 = __shfl(linv, rbase + 1, 64);
  float i2 = __shfl(linv, rbase + 2, 64);
  float i3 = __shfl(linv, rbase + 3, 64);
  float invs[4] = {i0, i1, i2, i3};
#pragma unroll
  for (int dd = 0; dd < 4; dd++) {
#pragma unroll
    for (int r = 0; r < 4; r++) {
      size_t idx = (size_t)(b * 2048 + q0 + rbase + r) * 1024 + h * 64 + 16 * dd + lr;
      ctxh[idx] = (_Float16)(cacc[dd][r] * invs[r]);
    }
  }
}

extern "C" void kernel_launch(void* const* d_in, const int* in_sizes, int n_in,
                              void* d_out, int out_size, void* d_ws, size_t ws_size,
                              hipStream_t stream) {
  const float* x    = (const float*)d_in[0];
  const int*   mask = (const int*)d_in[1];
  const float* Wq   = (const float*)d_in[2];
  const float* bq   = (const float*)d_in[3];
  const float* Wk   = (const float*)d_in[4];
  const float* bk   = (const float*)d_in[5];
  const float* Wv   = (const float*)d_in[6];
  const float* bv   = (const float*)d_in[7];
  const float* Wo   = (const float*)d_in[8];
  const float* bo   = (const float*)d_in[9];
  const float* Wm1  = (const float*)d_in[10];
  const float* bm1  = (const float*)d_in[11];
  const float* Wm2  = (const float*)d_in[12];
  const float* bm2  = (const float*)d_in[13];
  float* outp = (float*)d_out;
  float* mech_out = outp + (size_t)MTOT * DMODEL;

  char* ws = (char*)d_ws;
  _Float16* xh   = (_Float16*)(ws + 0);
  _Float16* wqh  = (_Float16*)(ws + 8388608);
  _Float16* wkh  = (_Float16*)(ws + 10485760);
  _Float16* wvh  = (_Float16*)(ws + 12582912);
  _Float16* woh  = (_Float16*)(ws + 14680064);
  _Float16* wm1h = (_Float16*)(ws + 16777216);
  _Float16* Qh   = (_Float16*)(ws + 17825792);
  _Float16* Kh   = (_Float16*)(ws + 26214400);
  _Float16* Vh   = (_Float16*)(ws + 34603008);
  _Float16* VT   = (_Float16*)(ws + 42991616);
  _Float16* ctxh = (_Float16*)(ws + 51380224);
  _Float16* Hm   = (_Float16*)(ws + 59768832);
  float* logits  = (float*)(ws + 63963136);
  float* mech_ws = (float*)(ws + 63979520);

  hipLaunchKernelGGL(cvt_all_kernel, dim3(4608, 2), dim3(256), 0, stream,
                     x, Wq, Wk, Wv, Wo, Wm1, xh, wqh, wkh, wvh, woh, wm1h);

  hipLaunchKernelGGL(proj_kernel, dim3(32, 8, 4), dim3(256), 0, stream,
                     xh, wqh, wkh, wvh, wm1h, bq, bk, bv, bm1, Qh, Kh, Vh, Hm);

  hipLaunchKernelGGL(mech_logits_kernel, dim3(1024), dim3(256), 0, stream,
                     Hm, Wm2, bm2, logits);
  hipLaunchKernelGGL(mech_softmax_kernel, dim3(2), dim3(256), 0, stream,
                     logits, mech_ws, mech_out);

  hipLaunchKernelGGL(vtrans_kernel, dim3(32, 32), dim3(256), 0, stream, Vh, VT);

  hipLaunchKernelGGL(attn_kernel, dim3(32, 32), dim3(256), 0, stream,
                     Qh, Kh, VT, mech_ws, mask, ctxh);

  hipLaunchKernelGGL(outproj_kernel, dim3(32, 8), dim3(256), 0, stream,
                     ctxh, woh, bo, outp);
}